// Round 6
// baseline (250.563 us; speedup 1.0000x reference)
//
#include <hip/hip_runtime.h>

// R6 — DIAGNOSTIC PROBE, intentional ~2x matcher work (output identical).
// Purpose: decompose dur_us. Five structurally different matchers all land at
// 121.3-121.7 us; the matcher's own dispatch never appears in top-5 (hidden
// below the ~58us poison fills). Two models fit: (A) matcher ~55us, stalled on
// an unidentified invariant; (B) matcher ~22us (near its 19-20us roofline) and
// ~40us is the harness's tiny-memset launch-latency floor.
// This kernel runs the row loop TWICE (second pass rewrites identical values;
// asm memory clobber between passes blocks dead-store elimination), so:
//   dur_us ~= 121.5 + M  where M = true matcher time.
// If M>=~55 the doubled matcher (~110us) surfaces in top-5 WITH its counters.
// Will revert to single-pass next round; M picks the follow-up strategy.

#define NC 91
#define TT 1600
#define T4 (TT / 4)         // 400 float4 columns
#define ROWS 16
#define NTHREADS 448
#define TABN (ROWS * NC)    // 1456 floats
#define TAB4 (TABN / 4)     // 364 float4

typedef float vfloat4 __attribute__((ext_vector_type(4)));

__device__ __forceinline__ float focal_tab(float x) {
    const float p = __builtin_amdgcn_rcpf(1.f + __expf(-x));  // sigmoid
    const float omp = 1.f - p;
    const float neg = 0.75f * p * p * (-__logf(omp + 1e-8f));
    const float pos = 0.25f * omp * omp * (-__logf(p + 1e-8f));
    return 2.f * (pos - neg) + 2.f;   // fold COST_CLASS and giou's "+1"
}

__global__ __launch_bounds__(NTHREADS, 4) void matcher_kernel(
    const float* __restrict__ logits,      // [N, 91]
    const float4* __restrict__ pboxes,     // [N] (cx,cy,w,h)
    const int4* __restrict__ tids,         // [T/4]
    const float4* __restrict__ tboxes,     // [T] (cx,cy,w,h)
    vfloat4* __restrict__ out)             // [N, T/4]
{
    __shared__ float tab[TABN];            // flat [ROWS][NC]

    const int n0 = blockIdx.x * ROWS;
    const int tid = threadIdx.x;
    const bool active = (tid < T4);

    // --- issue t-side vector loads FIRST; latency hides under tab build ---
    int4 ids = {0, 0, 0, 0};
    float4 tb[4];
    if (active) {
        ids = tids[tid];
#pragma unroll
        for (int j = 0; j < 4; ++j) tb[j] = tboxes[tid * 4 + j];
    }

    // --- prologue: coalesced float4 logits -> elementwise focal -> LDS ---
    if (tid < TAB4) {
        const float4 v = *reinterpret_cast<const float4*>(
            logits + (size_t)n0 * NC + 4 * (size_t)tid);
        float4 o;
        o.x = focal_tab(v.x);
        o.y = focal_tab(v.y);
        o.z = focal_tab(v.z);
        o.w = focal_tab(v.w);
        *reinterpret_cast<float4*>(&tab[4 * tid]) = o;
    }
    __syncthreads();

    if (!active) return;

    const int idv[4] = {ids.x, ids.y, ids.z, ids.w};
    float tx0[4], ty0[4], tx1[4], ty1[4];
#pragma unroll
    for (int j = 0; j < 4; ++j) {
        tx0[j] = tb[j].x - 0.5f * tb[j].z;
        ty0[j] = tb[j].y - 0.5f * tb[j].w;
        tx1[j] = tb[j].x + 0.5f * tb[j].z;
        ty1[j] = tb[j].y + 0.5f * tb[j].w;
    }

    // ===== PROBE: run the full output pass twice (idempotent) =====
    for (int rep = 0; rep < 2; ++rep) {
#pragma unroll
        for (int r = 0; r < ROWS; ++r) {
            const float4 b = pboxes[n0 + r];   // block-uniform -> s_load
            const float pcx = b.x, pcy = b.y, pw = b.z, ph = b.w;
            const float px0 = pcx - 0.5f * pw, py0 = pcy - 0.5f * ph;
            const float px1 = pcx + 0.5f * pw, py1 = pcy + 0.5f * ph;
            const float pa  = pw * ph;
            vfloat4 res;
#pragma unroll
            for (int j = 0; j < 4; ++j) {
                const float tw = tx1[j] - tx0[j];
                const float th = ty1[j] - ty0[j];
                const float iwr = fminf(px1, tx1[j]) - fmaxf(px0, tx0[j]);
                const float ihr = fminf(py1, ty1[j]) - fmaxf(py0, ty0[j]);
                const float inter = fmaxf(iwr, 0.f) * fmaxf(ihr, 0.f);
                const float uni = pa + tw * th - inter;
                const float ew = (pw + tw) - iwr;
                const float eh = (ph + th) - ihr;
                const float ae = ew * eh;
                const float tcx = tx0[j] + 0.5f * tw;
                const float tcy = ty0[j] + 0.5f * th;
                const float l1 = fabsf(pcx - tcx) + fabsf(pcy - tcy)
                               + fabsf(pw - tw) + fabsf(ph - th);
                res[j] = 5.f * l1 + tab[r * NC + idv[j]]
                       - 2.f * inter * __builtin_amdgcn_rcpf(uni)
                       - 2.f * uni * __builtin_amdgcn_rcpf(ae);
            }
            out[(size_t)(n0 + r) * T4 + tid] = res;
        }
        // block dead-store elimination / pass merging across reps
        asm volatile("" ::: "memory");
    }
}

extern "C" void kernel_launch(void* const* d_in, const int* in_sizes, int n_in,
                              void* d_out, int out_size, void* d_ws, size_t ws_size,
                              hipStream_t stream) {
    const float* logits  = (const float*)d_in[0];
    const float4* pboxes = (const float4*)d_in[1];
    const int4* tids     = (const int4*)d_in[2];
    const float4* tboxes = (const float4*)d_in[3];
    vfloat4* out = (vfloat4*)d_out;
    const int N = in_sizes[1] / 4;  // 14400 rows
    matcher_kernel<<<N / ROWS, NTHREADS, 0, stream>>>(logits, pboxes, tids, tboxes, out);
}

// Round 7
// 122.075 us; speedup vs baseline: 2.0525x; 2.0525x over previous
//
#include <hip/hip_runtime.h>

// HungarianMatcher cost matrix: C[n,t] = 5*L1(box_n,box_t) + 2*(pos-neg)[n,id_t] - 2*GIoU(n,t)
// bs=16, nq=900 -> N=14400 rows; T=1600 targets; nc=91 classes.
// R7: R5 single-pass structure + STREAMING STORES (sc0 sc1 nt) — single change.
// R6 probe (2x pass) exposed the bottleneck: FETCH_SIZE=190MB ~= 2x out-buffer
// for a kernel with ~6MB logical reads -> plain global_store write-ALLOCATES
// in L2 (each store-miss fetches the 128B line from HBM first). Store path
// saturates at ~1.9 TB/s; all pipes idle (VALU 11.7%, HBM 37%). The harness
// fill writes the same buffer at 6.27 TB/s with FETCH=14.5KB -> a no-allocate
// streaming path exists. __builtin_nontemporal_store (R0) only sets `nt`
// (eviction hint, still allocates -> neutral). The no-allocate policy bits on
// gfx950 are sc0+sc1 -> inline asm global_store_dwordx4 ... sc0 sc1 nt.
// Predicted: matcher FETCH ~97MB -> ~6MB, matcher ~55us -> ~20-25us,
// dur_us 121.5 -> ~90-97.

#define NC 91
#define TT 1600
#define T4 (TT / 4)         // 400 float4 columns
#define ROWS 16
#define NTHREADS 448
#define TABN (ROWS * NC)    // 1456 floats
#define TAB4 (TABN / 4)     // 364 float4

typedef float vfloat4 __attribute__((ext_vector_type(4)));

__device__ __forceinline__ float focal_tab(float x) {
    const float p = __builtin_amdgcn_rcpf(1.f + __expf(-x));  // sigmoid
    const float omp = 1.f - p;
    const float neg = 0.75f * p * p * (-__logf(omp + 1e-8f));
    const float pos = 0.25f * omp * omp * (-__logf(p + 1e-8f));
    return 2.f * (pos - neg) + 2.f;   // fold COST_CLASS and giou's "+1"
}

__device__ __forceinline__ void store_stream(vfloat4* addr, vfloat4 v) {
    // no-allocate streaming store: sc0 sc1 = system-scope (bypass L2 allocate),
    // nt = non-temporal. Same policy the rocclr fill kernel uses (FETCH~0).
    asm volatile("global_store_dwordx4 %0, %1, off sc0 sc1 nt"
                 :: "v"(addr), "v"(v)
                 : "memory");
}

__global__ __launch_bounds__(NTHREADS, 4) void matcher_kernel(
    const float* __restrict__ logits,      // [N, 91]
    const float4* __restrict__ pboxes,     // [N] (cx,cy,w,h)
    const int4* __restrict__ tids,         // [T/4]
    const float4* __restrict__ tboxes,     // [T] (cx,cy,w,h)
    vfloat4* __restrict__ out)             // [N, T/4]
{
    __shared__ float tab[TABN];            // flat [ROWS][NC]

    const int n0 = blockIdx.x * ROWS;
    const int tid = threadIdx.x;
    const bool active = (tid < T4);

    // --- issue t-side vector loads FIRST; latency hides under tab build ---
    int4 ids = {0, 0, 0, 0};
    float4 tb[4];
    if (active) {
        ids = tids[tid];
#pragma unroll
        for (int j = 0; j < 4; ++j) tb[j] = tboxes[tid * 4 + j];
    }

    // --- prologue: coalesced float4 logits -> elementwise focal -> LDS ---
    if (tid < TAB4) {
        const float4 v = *reinterpret_cast<const float4*>(
            logits + (size_t)n0 * NC + 4 * (size_t)tid);
        float4 o;
        o.x = focal_tab(v.x);
        o.y = focal_tab(v.y);
        o.z = focal_tab(v.z);
        o.w = focal_tab(v.w);
        *reinterpret_cast<float4*>(&tab[4 * tid]) = o;
    }
    __syncthreads();

    if (!active) return;

    const int idv[4] = {ids.x, ids.y, ids.z, ids.w};
    // keep ONLY corners in VGPRs (16 regs of target state)
    float tx0[4], ty0[4], tx1[4], ty1[4];
#pragma unroll
    for (int j = 0; j < 4; ++j) {
        tx0[j] = tb[j].x - 0.5f * tb[j].z;
        ty0[j] = tb[j].y - 0.5f * tb[j].w;
        tx1[j] = tb[j].x + 0.5f * tb[j].z;
        ty1[j] = tb[j].y + 0.5f * tb[j].w;
    }

#pragma unroll
    for (int r = 0; r < ROWS; ++r) {
        // block-uniform address -> scalar load, lives in SGPRs (no VGPR cost)
        const float4 b = pboxes[n0 + r];
        const float pcx = b.x, pcy = b.y, pw = b.z, ph = b.w;
        const float px0 = pcx - 0.5f * pw, py0 = pcy - 0.5f * ph;
        const float px1 = pcx + 0.5f * pw, py1 = pcy + 0.5f * ph;
        const float pa  = pw * ph;
        vfloat4 res;
#pragma unroll
        for (int j = 0; j < 4; ++j) {
            const float tw = tx1[j] - tx0[j];
            const float th = ty1[j] - ty0[j];
            // intersection (raw, may be negative)
            const float iwr = fminf(px1, tx1[j]) - fmaxf(px0, tx0[j]);
            const float ihr = fminf(py1, ty1[j]) - fmaxf(py0, ty0[j]);
            const float inter = fmaxf(iwr, 0.f) * fmaxf(ihr, 0.f);
            const float uni = pa + tw * th - inter;
            // enclosing box via min+max identity (clamp is a no-op: w,h>=0)
            const float ew = (pw + tw) - iwr;
            const float eh = (ph + th) - ihr;
            const float ae = ew * eh;
            const float tcx = tx0[j] + 0.5f * tw;
            const float tcy = ty0[j] + 0.5f * th;
            const float l1 = fabsf(pcx - tcx) + fabsf(pcy - tcy)
                           + fabsf(pw - tw) + fabsf(ph - th);
            // res = 5*L1 + [2*(pos-neg)+2] - 2*inter/uni - 2*uni/ae
            res[j] = 5.f * l1 + tab[r * NC + idv[j]]
                   - 2.f * inter * __builtin_amdgcn_rcpf(uni)
                   - 2.f * uni * __builtin_amdgcn_rcpf(ae);
        }
        store_stream(&out[(size_t)(n0 + r) * T4 + tid], res);
    }
}

extern "C" void kernel_launch(void* const* d_in, const int* in_sizes, int n_in,
                              void* d_out, int out_size, void* d_ws, size_t ws_size,
                              hipStream_t stream) {
    const float* logits  = (const float*)d_in[0];
    const float4* pboxes = (const float4*)d_in[1];
    const int4* tids     = (const int4*)d_in[2];
    const float4* tboxes = (const float4*)d_in[3];
    vfloat4* out = (vfloat4*)d_out;
    const int N = in_sizes[1] / 4;  // 14400 rows
    matcher_kernel<<<N / ROWS, NTHREADS, 0, stream>>>(logits, pboxes, tids, tboxes, out);
}